// Round 6
// baseline (1017.254 us; speedup 1.0000x reference)
//
#include <hip/hip_runtime.h>
#include <hip/hip_fp16.h>
#include <hip/hip_cooperative_groups.h>

namespace cg = cooperative_groups;

#define B_ 64
#define F_ 4
#define M_ 4096
#define D_ 1024
#define W_ 16      // u64 words per D bits
#define CW_ 64     // u64 words per M bits
#define NITER 15

typedef _Float16 f16;
typedef _Float16 f16x8 __attribute__((ext_vector_type(8)));
typedef float f32x4 __attribute__((ext_vector_type(4)));
typedef unsigned int u32;
typedef unsigned short u16;
typedef unsigned long long u64;

// ---- device-global scratch (rebuilt every call) ----
__device__ __align__(16) u64 g_cbBits[F_ * M_ * W_];    // 2 MB: cb packed along d
__device__ __align__(16) u64 g_colBits[F_ * D_ * CW_];  // 2 MB: cb packed along m
__device__ __align__(16) f16 g_G[F_ * D_ * D_];         // 8 MB: G = cb^T cb (even ints <=4096, exact fp16)
__device__ __align__(16) u64 g_inBits[B_ * W_];
__device__ __align__(16) u64 g_est[2][B_ * F_ * W_];    // ping-pong packed estimates
__device__ int g_mismatch[16];
__device__ int g_iters;
__device__ int g_conv;

__device__ __forceinline__ u32 nib16(u32 x) {
    x &= 0x0F0F0F0Fu;
    x = (x | (x >> 4)) & 0x00FF00FFu;
    x = (x | (x >> 8)) & 0x0000FFFFu;
    return x;
}

// ---- bit-pack via nibble-LDS: no ballots, full MLP, all accesses coalesced ----
__global__ __launch_bounds__(256) void k_pack(const float* __restrict__ inp,
                                              const float* __restrict__ est0,
                                              const float* __restrict__ cb) {
    __shared__ unsigned char nib[4096];   // 4 waves x 4 rows x 256 nibbles
    int blk = blockIdx.x, tid = threadIdx.x;
    int wv = tid >> 6, lane = tid & 63;
    const float* src; u64* dst; int r0;
    if (blk < 1024)      { src = cb;   dst = g_cbBits; r0 = blk * 16; }
    else if (blk < 1040) { src = est0; dst = g_est[0]; r0 = (blk - 1024) * 16; }
    else if (blk < 1044) { src = inp;  dst = g_inBits; r0 = (blk - 1040) * 16; }
    else {
        if (tid < 16) g_mismatch[tid] = 0;
        else if (tid == 16) g_iters = 0;
        else if (tid == 17) g_conv = 0;
        return;
    }
    int rw = r0 + wv * 4;
    unsigned char* mynib = nib + wv * 1024;
    #pragma unroll
    for (int rr = 0; rr < 4; rr++) {
        const float4* s4 = (const float4*)(src + (size_t)(rw + rr) * D_);
        #pragma unroll
        for (int it = 0; it < 4; it++) {
            float4 v = s4[it * 64 + lane];
            u32 n = (__float_as_uint(v.x) >> 31)
                  | (((__float_as_uint(v.y) >> 31)) << 1)
                  | (((__float_as_uint(v.z) >> 31)) << 2)
                  | (((__float_as_uint(v.w) >> 31)) << 3);
            mynib[rr * 256 + it * 64 + lane] = (unsigned char)n;
        }
    }
    uint4 q = *(const uint4*)(mynib + (lane >> 4) * 256 + (lane & 15) * 16);
    u32 w0 = nib16(q.x), w1 = nib16(q.y), w2 = nib16(q.z), w3 = nib16(q.w);
    u64 word = (u64)(w0 | (w1 << 16)) | ((u64)(w2 | (w3 << 16)) << 32);
    dst[(size_t)(rw + (lane >> 4)) * W_ + (lane & 15)] = word;
}

// ---- 64x64 bit-transpose: cbBits[m][wd] -> colBits[d][wm] ----
__global__ __launch_bounds__(256) void k_bitT() {
    int tid = threadIdx.x, wv = tid >> 6, lane = tid & 63;
    int tbase = (blockIdx.x * 4 + wv) * 4;
    for (int q = 0; q < 4; q++) {
        int task = tbase + q;
        int mt = task & 63;
        int wd = (task >> 6) & 15;
        int f  = task >> 10;
        u64 row = g_cbBits[((size_t)(f * M_ + mt * 64 + lane)) * W_ + wd];
        u64 myout = 0;
        #pragma unroll
        for (int j = 0; j < 64; j++) {
            u64 t = __ballot((row >> j) & 1ULL);
            if (lane == j) myout = t;
        }
        g_colBits[((size_t)(f * D_ + wd * 64 + lane)) * CW_ + mt] = myout;
    }
}

// ---- G = cb^T cb, symmetric: only t1<=t2 pairs; mirror via LDS transpose ----
__global__ __launch_bounds__(256) void k_G() {
    int blk = blockIdx.x;                  // 544 = f(4) x 136 pairs
    int f = blk / 136;
    int pi = blk % 136;
    int t1 = 0;
    while (pi >= 16 - t1) { pi -= 16 - t1; t1++; }
    int t2 = t1 + pi;
    __shared__ u64 L1T[64][64];            // [w][d_loc]
    __shared__ u64 L2T[64][64];
    int tid = threadIdx.x;
    int wv = tid >> 6, lane = tid & 63;
    for (int it = 0; it < 16; it++) {
        int w = it * 4 + wv;
        L1T[w][lane] = g_colBits[((size_t)(f * D_ + t1 * 64 + lane)) * CW_ + w];
        L2T[w][lane] = g_colBits[((size_t)(f * D_ + t2 * 64 + lane)) * CW_ + w];
    }
    __syncthreads();
    int g1 = tid >> 4, g2 = tid & 15;
    int p[4][4] = {};
    for (int w = 0; w < 64; w++) {
        u64 a0 = L1T[w][g1], a1 = L1T[w][g1 + 16], a2 = L1T[w][g1 + 32], a3 = L1T[w][g1 + 48];
        u64 b0 = L2T[w][g2], b1 = L2T[w][g2 + 16], b2 = L2T[w][g2 + 32], b3 = L2T[w][g2 + 48];
        p[0][0] += __popcll(a0 ^ b0); p[0][1] += __popcll(a0 ^ b1);
        p[0][2] += __popcll(a0 ^ b2); p[0][3] += __popcll(a0 ^ b3);
        p[1][0] += __popcll(a1 ^ b0); p[1][1] += __popcll(a1 ^ b1);
        p[1][2] += __popcll(a1 ^ b2); p[1][3] += __popcll(a1 ^ b3);
        p[2][0] += __popcll(a2 ^ b0); p[2][1] += __popcll(a2 ^ b1);
        p[2][2] += __popcll(a2 ^ b2); p[2][3] += __popcll(a2 ^ b3);
        p[3][0] += __popcll(a3 ^ b0); p[3][1] += __popcll(a3 ^ b1);
        p[3][2] += __popcll(a3 ^ b2); p[3][3] += __popcll(a3 ^ b3);
    }
    #pragma unroll
    for (int i = 0; i < 4; i++) {
        int d1 = t1 * 64 + g1 + 16 * i;
        #pragma unroll
        for (int j = 0; j < 4; j++) {
            int d2 = t2 * 64 + g2 + 16 * j;
            g_G[((size_t)(f * D_ + d1)) * D_ + d2] = (f16)(M_ - 2 * p[i][j]);
        }
    }
    if (t1 == t2) return;
    // mirror tile via LDS transpose (stride 72 keeps rows 16B-aligned)
    __syncthreads();
    f16* Lt = (f16*)L1T;
    #pragma unroll
    for (int i = 0; i < 4; i++)
        #pragma unroll
        for (int j = 0; j < 4; j++)
            Lt[(g2 + 16 * j) * 72 + (g1 + 16 * i)] = (f16)(M_ - 2 * p[i][j]);
    __syncthreads();
    int r = tid >> 2, c0 = (tid & 3) * 16;          // 64 rows x 64 cols, 16 f16/thread
    const uint4* s = (const uint4*)&Lt[r * 72 + c0];
    uint4 v0 = s[0], v1 = s[1];
    uint4* dsto = (uint4*)&g_G[((size_t)(f * D_ + t2 * 64 + r)) * D_ + t1 * 64 + c0];
    dsto[0] = v0; dsto[1] = v1;
}

__device__ __forceinline__ u32 pairval(u32 bits, int i) {
    // two bits -> two fp16: 0x3C00 (+1) / 0xBC00 (-1)
    return 0x3C003C00u | (((bits >> i) & 1u) << 15) | (((bits >> (i + 1)) & 1u) << 31);
}

// ---- fused 15-iteration resonator loop + final cleanup (cooperative) ----
__global__ __launch_bounds__(256) void k_loop(float* __restrict__ out) {
    cg::grid_group grid = cg::this_grid();
    int blk = blockIdx.x;                           // 256 = f(4) x dt(64)
    int f = blk >> 6, dt = blk & 63;
    int tid = threadIdx.x;
    int wv = tid >> 6, lane = tid & 63;
    __shared__ u64 neL[64][17];
    __shared__ __align__(16) char ldsB[16 * 2048];  // resident G slice, XOR-swizzled
    __shared__ int red[256];
    {   // stage this block's 16 G-rows ONCE
        const char* gsrc = (const char*)(g_G + ((size_t)(f * D_ + dt * 16)) * D_);
        for (int i = tid; i < 2048; i += 256) {
            int row = i >> 7, col = i & 127;
            uint4 v = *(const uint4*)(gsrc + (size_t)row * 2048 + col * 16);
            *(uint4*)(ldsB + row * 2048 + ((col * 16) ^ ((row & 7) << 4))) = v;
        }
    }
    const unsigned char* neB = (const unsigned char*)neL;
    int dd = lane & 15;
    int gg = lane >> 4;
    int aRow = wv * 16 + dd;
    int aBase = aRow * 136 + gg;
    for (int t = 0; t < NITER; t++) {
        const u64* rb = g_est[t & 1];
        u64* wb = g_est[(t + 1) & 1];
        if (blk == 0 && tid == 0) {                 // fold previous iter's convergence
            if (t > 0 && g_mismatch[t - 1] == 0) g_conv = 1;
            if (!g_conv) g_iters++;
        }
        for (int idx = tid; idx < 1024; idx += 256) {   // ne = in * prod_{j!=f} est_j
            int b = idx >> 4, w = idx & 15;
            u64 e0 = rb[(b * 4 + 0) * W_ + w];
            u64 e1 = rb[(b * 4 + 1) * W_ + w];
            u64 e2 = rb[(b * 4 + 2) * W_ + w];
            u64 e3 = rb[(b * 4 + 3) * W_ + w];
            u64 x = g_inBits[b * W_ + w] ^ e0 ^ e1 ^ e2 ^ e3;
            u64 ef = (f == 0) ? e0 : (f == 1) ? e1 : (f == 2) ? e2 : e3;
            neL[b][w] = x ^ ef;
        }
        __syncthreads();
        f32x4 acc0 = {}, acc1 = {};
        #pragma unroll
        for (int c = 0; c < 32; c++) {
            u32 bits = neB[aBase + c * 4];
            f16x8 a;
            ((u32*)&a)[0] = pairval(bits, 0);
            ((u32*)&a)[1] = pairval(bits, 2);
            ((u32*)&a)[2] = pairval(bits, 4);
            ((u32*)&a)[3] = pairval(bits, 6);
            f16x8 bf = *(const f16x8*)(ldsB + dd * 2048 +
                                       (((c * 64) + gg * 16) ^ ((dd & 7) << 4)));
            if (c & 1) acc1 = __builtin_amdgcn_mfma_f32_16x16x32_f16(a, bf, acc1, 0, 0, 0);
            else       acc0 = __builtin_amdgcn_mfma_f32_16x16x32_f16(a, bf, acc0, 0, 0, 0);
        }
        u16* wb16 = (u16*)wb;
        const u16* rb16 = (const u16*)rb;
        int mm = 0;
        #pragma unroll
        for (int j = 0; j < 4; j++) {
            float v = acc0[j] + acc1[j];            // exact int
            u64 mask = __ballot(v < 0.0f);
            if ((lane & 15) == 0) {
                int b = wv * 16 + gg * 4 + j;
                u16 nv = (u16)(mask >> (gg * 16));
                int oi = (b * 4 + f) * 64 + dt;
                if (rb16[oi] != nv) mm = 1;
                wb16[oi] = nv;
            }
        }
        u64 anym = __ballot(mm != 0);
        if (lane == 0 && anym) atomicOr(&g_mismatch[t], 1);
        __threadfence();
        grid.sync();                                // next iter reads wb
    }
    // ---- final cleanup, block = (bb, ff) ----
    const u64* eb_g = g_est[NITER & 1];
    if (blk == 0 && tid == 0) {
        if (g_mismatch[NITER - 1] == 0) g_conv = 1;
        out[256 + 262144] = (float)g_iters;
        out[256 + 262144 + 1] = (float)g_conv;
    }
    int bb = blk >> 2, ff = blk & 3;
    for (int j = 0; j < 4; j++) {
        int d = j * 256 + tid;
        u64 w = eb_g[(size_t)(bb * 4 + ff) * W_ + (d >> 6)];
        out[256 + ((size_t)(bb * 4 + ff)) * D_ + d] = ((w >> (d & 63)) & 1) ? -1.0f : 1.0f;
    }
    u64 eb[W_];
    #pragma unroll
    for (int w = 0; w < W_; w++) eb[w] = eb_g[(size_t)(bb * 4 + ff) * W_ + w];
    int bestKey = -1;
    for (int j = 0; j < 16; j++) {
        int m = j * 256 + tid;
        int p = 0;
        #pragma unroll
        for (int w = 0; w < W_; w++)
            p += __popcll(eb[w] ^ g_cbBits[((size_t)(ff * M_ + m)) * W_ + w]);
        int s = D_ - 2 * p;
        int a = s < 0 ? -s : s;
        int key = (a << 12) | (4095 - m);   // max |sim|, then min m
        if (key > bestKey) bestKey = key;
    }
    red[tid] = bestKey;
    __syncthreads();
    for (int off = 128; off > 0; off >>= 1) {
        if (tid < off) red[tid] = max(red[tid], red[tid + off]);
        __syncthreads();
    }
    if (tid == 0) out[bb * 4 + ff] = (float)(4095 - (red[0] & 0xFFF));
}

extern "C" void kernel_launch(void* const* d_in, const int* in_sizes, int n_in,
                              void* d_out, int out_size, void* d_ws, size_t ws_size,
                              hipStream_t stream) {
    (void)d_ws; (void)ws_size;
    const float* inp  = (const float*)d_in[0];
    const float* est0 = (const float*)d_in[1];
    const float* cb   = (const float*)d_in[2];
    float* out = (float*)d_out;

    k_pack<<<1045, 256, 0, stream>>>(inp, est0, cb);
    k_bitT<<<256, 256, 0, stream>>>();
    k_G<<<544, 256, 0, stream>>>();
    void* args[] = { (void*)&out };
    hipLaunchCooperativeKernel(reinterpret_cast<void*>(k_loop), dim3(256), dim3(256),
                               args, 0, stream);
}

// Round 7
// 393.928 us; speedup vs baseline: 2.5823x; 2.5823x over previous
//
#include <hip/hip_runtime.h>
#include <hip/hip_fp16.h>

#define B_ 64
#define F_ 4
#define M_ 4096
#define D_ 1024
#define W_ 16      // u64 words per D bits
#define CW_ 64     // u64 words per M bits
#define NITER 15
#define NBLK_LOOP 128

typedef _Float16 f16;
typedef _Float16 f16x8 __attribute__((ext_vector_type(8)));
typedef float f32x4 __attribute__((ext_vector_type(4)));
typedef unsigned int u32;
typedef unsigned short u16;
typedef unsigned long long u64;

#define LD_AG(p)     __hip_atomic_load((p), __ATOMIC_RELAXED, __HIP_MEMORY_SCOPE_AGENT)
#define ST_AG(p, v)  __hip_atomic_store((p), (v), __ATOMIC_RELAXED, __HIP_MEMORY_SCOPE_AGENT)

// ---- device-global scratch (rebuilt every call) ----
__device__ __align__(16) u64 g_cbBits[F_ * M_ * W_];    // 2 MB: cb packed along d
__device__ __align__(16) u64 g_colBits[F_ * D_ * CW_];  // 2 MB: cb packed along m
__device__ __align__(16) f16 g_G[F_ * D_ * D_];         // 8 MB: G = cb^T cb (even ints <=4096, exact fp16)
__device__ __align__(16) u64 g_inBits[B_ * W_];
__device__ __align__(16) u64 g_est[2][B_ * F_ * W_];    // ping-pong packed estimates
__device__ int g_mismatch[16];
__device__ u32 g_bar[16];
__device__ int g_iters;
__device__ int g_conv;

__device__ __forceinline__ u32 nib16(u32 x) {
    x &= 0x0F0F0F0Fu;
    x = (x | (x >> 4)) & 0x00FF00FFu;
    x = (x | (x >> 8)) & 0x0000FFFFu;
    return x;
}

// ---- bit-pack via nibble-LDS: no ballots, full MLP, all accesses coalesced ----
__global__ __launch_bounds__(256) void k_pack(const float* __restrict__ inp,
                                              const float* __restrict__ est0,
                                              const float* __restrict__ cb) {
    __shared__ unsigned char nib[4096];   // 4 waves x 4 rows x 256 nibbles
    int blk = blockIdx.x, tid = threadIdx.x;
    int wv = tid >> 6, lane = tid & 63;
    const float* src; u64* dst; int r0;
    if (blk < 1024)      { src = cb;   dst = g_cbBits; r0 = blk * 16; }
    else if (blk < 1040) { src = est0; dst = g_est[0]; r0 = (blk - 1024) * 16; }
    else if (blk < 1044) { src = inp;  dst = g_inBits; r0 = (blk - 1040) * 16; }
    else {
        if (tid < 16) g_mismatch[tid] = 0;
        else if (tid < 32) g_bar[tid - 16] = 0;
        else if (tid == 32) g_iters = 0;
        else if (tid == 33) g_conv = 0;
        return;
    }
    int rw = r0 + wv * 4;
    unsigned char* mynib = nib + wv * 1024;
    #pragma unroll
    for (int rr = 0; rr < 4; rr++) {
        const float4* s4 = (const float4*)(src + (size_t)(rw + rr) * D_);
        #pragma unroll
        for (int it = 0; it < 4; it++) {
            float4 v = s4[it * 64 + lane];
            u32 n = (__float_as_uint(v.x) >> 31)
                  | (((__float_as_uint(v.y) >> 31)) << 1)
                  | (((__float_as_uint(v.z) >> 31)) << 2)
                  | (((__float_as_uint(v.w) >> 31)) << 3);
            mynib[rr * 256 + it * 64 + lane] = (unsigned char)n;
        }
    }
    uint4 q = *(const uint4*)(mynib + (lane >> 4) * 256 + (lane & 15) * 16);
    u32 w0 = nib16(q.x), w1 = nib16(q.y), w2 = nib16(q.z), w3 = nib16(q.w);
    u64 word = (u64)(w0 | (w1 << 16)) | ((u64)(w2 | (w3 << 16)) << 32);
    dst[(size_t)(rw + (lane >> 4)) * W_ + (lane & 15)] = word;
}

// ---- 64x64 bit-transpose: cbBits[m][wd] -> colBits[d][wm] ----
__global__ __launch_bounds__(256) void k_bitT() {
    int tid = threadIdx.x, wv = tid >> 6, lane = tid & 63;
    int tbase = (blockIdx.x * 4 + wv) * 4;
    for (int q = 0; q < 4; q++) {
        int task = tbase + q;
        int mt = task & 63;
        int wd = (task >> 6) & 15;
        int f  = task >> 10;
        u64 row = g_cbBits[((size_t)(f * M_ + mt * 64 + lane)) * W_ + wd];
        u64 myout = 0;
        #pragma unroll
        for (int j = 0; j < 64; j++) {
            u64 t = __ballot((row >> j) & 1ULL);
            if (lane == j) myout = t;
        }
        g_colBits[((size_t)(f * D_ + wd * 64 + lane)) * CW_ + mt] = myout;
    }
}

// ---- G = cb^T cb, symmetric: only t1<=t2 pairs; mirror via LDS transpose ----
__global__ __launch_bounds__(256) void k_G() {
    int blk = blockIdx.x;                  // 544 = f(4) x 136 pairs
    int f = blk / 136;
    int pi = blk % 136;
    int t1 = 0;
    while (pi >= 16 - t1) { pi -= 16 - t1; t1++; }
    int t2 = t1 + pi;
    __shared__ u64 L1T[64][64];            // [w][d_loc]
    __shared__ u64 L2T[64][64];
    int tid = threadIdx.x;
    int wv = tid >> 6, lane = tid & 63;
    for (int it = 0; it < 16; it++) {
        int w = it * 4 + wv;
        L1T[w][lane] = g_colBits[((size_t)(f * D_ + t1 * 64 + lane)) * CW_ + w];
        L2T[w][lane] = g_colBits[((size_t)(f * D_ + t2 * 64 + lane)) * CW_ + w];
    }
    __syncthreads();
    int g1 = tid >> 4, g2 = tid & 15;
    int p[4][4] = {};
    for (int w = 0; w < 64; w++) {
        u64 a0 = L1T[w][g1], a1 = L1T[w][g1 + 16], a2 = L1T[w][g1 + 32], a3 = L1T[w][g1 + 48];
        u64 b0 = L2T[w][g2], b1 = L2T[w][g2 + 16], b2 = L2T[w][g2 + 32], b3 = L2T[w][g2 + 48];
        p[0][0] += __popcll(a0 ^ b0); p[0][1] += __popcll(a0 ^ b1);
        p[0][2] += __popcll(a0 ^ b2); p[0][3] += __popcll(a0 ^ b3);
        p[1][0] += __popcll(a1 ^ b0); p[1][1] += __popcll(a1 ^ b1);
        p[1][2] += __popcll(a1 ^ b2); p[1][3] += __popcll(a1 ^ b3);
        p[2][0] += __popcll(a2 ^ b0); p[2][1] += __popcll(a2 ^ b1);
        p[2][2] += __popcll(a2 ^ b2); p[2][3] += __popcll(a2 ^ b3);
        p[3][0] += __popcll(a3 ^ b0); p[3][1] += __popcll(a3 ^ b1);
        p[3][2] += __popcll(a3 ^ b2); p[3][3] += __popcll(a3 ^ b3);
    }
    #pragma unroll
    for (int i = 0; i < 4; i++) {
        int d1 = t1 * 64 + g1 + 16 * i;
        #pragma unroll
        for (int j = 0; j < 4; j++) {
            int d2 = t2 * 64 + g2 + 16 * j;
            g_G[((size_t)(f * D_ + d1)) * D_ + d2] = (f16)(M_ - 2 * p[i][j]);
        }
    }
    if (t1 == t2) return;
    __syncthreads();
    f16* Lt = (f16*)L1T;
    #pragma unroll
    for (int i = 0; i < 4; i++)
        #pragma unroll
        for (int j = 0; j < 4; j++)
            Lt[(g2 + 16 * j) * 72 + (g1 + 16 * i)] = (f16)(M_ - 2 * p[i][j]);
    __syncthreads();
    int r = tid >> 2, c0 = (tid & 3) * 16;
    const uint4* s = (const uint4*)&Lt[r * 72 + c0];
    uint4 v0 = s[0], v1 = s[1];
    uint4* dsto = (uint4*)&g_G[((size_t)(f * D_ + t2 * 64 + r)) * D_ + t1 * 64 + c0];
    dsto[0] = v0; dsto[1] = v1;
}

__device__ __forceinline__ u32 pairval(u32 bits, int i) {
    // two bits -> two fp16: 0x3C00 (+1) / 0xBC00 (-1)
    return 0x3C003C00u | (((bits >> i) & 1u) << 15) | (((bits >> (i + 1)) & 1u) << 31);
}

// ---- fused 15-iter loop + cleanup; custom agent-scope barrier (no coop launch) ----
// 128 blocks = f(4) x dg(32); block owns d-cols [dg*32, dg*32+32); 1 block/CU resident.
__global__ __launch_bounds__(256) void k_loop(float* __restrict__ out) {
    int blk = blockIdx.x;
    int f = blk & 3, dg = blk >> 2;
    int tid = threadIdx.x;
    int wv = tid >> 6, lane = tid & 63;
    __shared__ u64 neL[64][17];
    __shared__ __align__(16) char ldsB[32 * 2048];  // 32 G-rows x 1024 k, XOR-swizzled
    __shared__ int red[256];
    {   // stage this block's G slice ONCE (plain loads; written by prior kernel)
        const char* gsrc = (const char*)(g_G + ((size_t)(f * D_ + dg * 32)) * D_);
        for (int i = tid; i < 4096; i += 256) {
            int row = i >> 7, col = i & 127;
            uint4 v = *(const uint4*)(gsrc + (size_t)row * 2048 + col * 16);
            *(uint4*)(ldsB + row * 2048 + ((col * 16) ^ ((row & 7) << 4))) = v;
        }
    }
    const unsigned char* neB = (const unsigned char*)neL;
    int dd = lane & 15, gg = lane >> 4;
    int aBase = (wv * 16 + dd) * 136 + gg;
    for (int t = 0; t < NITER; t++) {
        const u64* rb = g_est[t & 1];
        const u32* rb32 = (const u32*)rb;
        u32* wb32 = (u32*)g_est[(t + 1) & 1];
        if (blk == 0 && tid == 0) {                 // fold previous iter's convergence
            if (t > 0 && LD_AG(&g_mismatch[t - 1]) == 0) g_conv = 1;
            if (!g_conv) g_iters++;
        }
        for (int idx = tid; idx < 1024; idx += 256) {   // ne = in * prod_{j!=f} est_j
            int b = idx >> 4, w = idx & 15;
            u64 e0 = LD_AG(&rb[(b * 4 + 0) * W_ + w]);
            u64 e1 = LD_AG(&rb[(b * 4 + 1) * W_ + w]);
            u64 e2 = LD_AG(&rb[(b * 4 + 2) * W_ + w]);
            u64 e3 = LD_AG(&rb[(b * 4 + 3) * W_ + w]);
            u64 x = g_inBits[b * W_ + w] ^ e0 ^ e1 ^ e2 ^ e3;
            u64 ef = (f == 0) ? e0 : (f == 1) ? e1 : (f == 2) ? e2 : e3;
            neL[b][w] = x ^ ef;
        }
        __syncthreads();
        f32x4 acc[2][2] = {};
        #pragma unroll
        for (int c = 0; c < 32; c++) {
            u32 bits = neB[aBase + c * 4];
            f16x8 a;
            ((u32*)&a)[0] = pairval(bits, 0);
            ((u32*)&a)[1] = pairval(bits, 2);
            ((u32*)&a)[2] = pairval(bits, 4);
            ((u32*)&a)[3] = pairval(bits, 6);
            #pragma unroll
            for (int ct = 0; ct < 2; ct++) {
                int rowB = ct * 16 + dd;
                f16x8 bf = *(const f16x8*)(ldsB + rowB * 2048 +
                                           ((c * 64 + gg * 16) ^ ((rowB & 7) << 4)));
                acc[ct][c & 1] =
                    __builtin_amdgcn_mfma_f32_16x16x32_f16(a, bf, acc[ct][c & 1], 0, 0, 0);
            }
        }
        u64 msk[2][4];
        #pragma unroll
        for (int ct = 0; ct < 2; ct++)
            #pragma unroll
            for (int j = 0; j < 4; j++) {
                float v = acc[ct][0][j] + acc[ct][1][j];    // exact int
                msk[ct][j] = __ballot(v < 0.0f);
            }
        int mm = 0;
        if (dd == 0) {                              // writer lanes: one u32 per b
            #pragma unroll
            for (int j = 0; j < 4; j++) {
                int b = wv * 16 + gg * 4 + j;
                u32 nv = (u32)((msk[0][j] >> (gg * 16)) & 0xFFFFu)
                       | ((u32)((msk[1][j] >> (gg * 16)) & 0xFFFFu) << 16);
                int oi = (b * 4 + f) * 32 + dg;
                u32 ov = LD_AG(&rb32[oi]);
                if (ov != nv) mm = 1;
                ST_AG(&wb32[oi], nv);
            }
        }
        u64 anym = __ballot(mm != 0);
        if (lane == 0 && anym)
            __hip_atomic_fetch_or(&g_mismatch[t], 1, __ATOMIC_RELAXED, __HIP_MEMORY_SCOPE_AGENT);
        __syncthreads();                            // block done with neL + stores issued
        if (tid == 0) {
            __hip_atomic_fetch_add(&g_bar[t], 1u, __ATOMIC_ACQ_REL, __HIP_MEMORY_SCOPE_AGENT);
            while (__hip_atomic_load(&g_bar[t], __ATOMIC_ACQUIRE, __HIP_MEMORY_SCOPE_AGENT)
                   < (u32)NBLK_LOOP)
                __builtin_amdgcn_s_sleep(2);
        }
        __syncthreads();
    }
    // ---- final cleanup: 2 (b,f) tasks per block ----
    const u64* eb_g = g_est[NITER & 1];
    if (blk == 0 && tid == 0) {
        int convf = g_conv;
        if (LD_AG(&g_mismatch[NITER - 1]) == 0) convf = 1;
        out[256 + 262144] = (float)g_iters;
        out[256 + 262144 + 1] = (float)convf;
    }
    for (int s = 0; s < 2; s++) {
        int task = blk * 2 + s;
        int bb = task >> 2, ff = task & 3;
        for (int j = 0; j < 4; j++) {
            int d = j * 256 + tid;
            u64 w = LD_AG(&eb_g[(size_t)(bb * 4 + ff) * W_ + (d >> 6)]);
            out[256 + ((size_t)(bb * 4 + ff)) * D_ + d] = ((w >> (d & 63)) & 1) ? -1.0f : 1.0f;
        }
        u64 eb[W_];
        #pragma unroll
        for (int w = 0; w < W_; w++) eb[w] = LD_AG(&eb_g[(size_t)(bb * 4 + ff) * W_ + w]);
        int bestKey = -1;
        for (int j = 0; j < 16; j++) {
            int m = j * 256 + tid;
            int p = 0;
            #pragma unroll
            for (int w = 0; w < W_; w++)
                p += __popcll(eb[w] ^ g_cbBits[((size_t)(ff * M_ + m)) * W_ + w]);
            int sv = D_ - 2 * p;
            int a = sv < 0 ? -sv : sv;
            int key = (a << 12) | (4095 - m);   // max |sim|, then min m
            if (key > bestKey) bestKey = key;
        }
        red[tid] = bestKey;
        __syncthreads();
        for (int off = 128; off > 0; off >>= 1) {
            if (tid < off) red[tid] = max(red[tid], red[tid + off]);
            __syncthreads();
        }
        if (tid == 0) out[bb * 4 + ff] = (float)(4095 - (red[0] & 0xFFF));
        __syncthreads();
    }
}

extern "C" void kernel_launch(void* const* d_in, const int* in_sizes, int n_in,
                              void* d_out, int out_size, void* d_ws, size_t ws_size,
                              hipStream_t stream) {
    (void)d_ws; (void)ws_size;
    const float* inp  = (const float*)d_in[0];
    const float* est0 = (const float*)d_in[1];
    const float* cb   = (const float*)d_in[2];
    float* out = (float*)d_out;

    k_pack<<<1045, 256, 0, stream>>>(inp, est0, cb);
    k_bitT<<<256, 256, 0, stream>>>();
    k_G<<<544, 256, 0, stream>>>();
    k_loop<<<NBLK_LOOP, 256, 0, stream>>>(out);
}